// Round 5
// baseline (502.918 us; speedup 1.0000x reference)
//
#include <hip/hip_runtime.h>
#include <math.h>

// Problem shape: B=65536 rows, C=1000 cols, fp32 inputs.
#define C_DIM 1000
#define NV4   250            // float4 per row
#define WPB   4              // waves per block
#define RPW   8              // rows per wave
#define CHUNK 256            // floats per 1 KB DMA chunk (64 lanes x 16 B)
#define ROWF  1024           // LDS floats per row stream (4 chunks)
#define PAD_O (-100.0f)      // exp(PAD_O)==0; with t=0 contributes nothing

#define GLOBAL_AS __attribute__((address_space(1)))
#define LDS_AS    __attribute__((address_space(3)))

__device__ __forceinline__ void dma16(const float* g, float* l) {
    // 64 lanes x 16 B -> LDS at (wave-uniform l) + lane*16. No dest VGPRs:
    // the compiler cannot sink this under register pressure.
    __builtin_amdgcn_global_load_lds((const GLOBAL_AS void*)g, (LDS_AS void*)l,
                                     16, 0, 0);
}

__device__ __forceinline__ float wave_sum(float v) {
#pragma unroll
    for (int off = 32; off > 0; off >>= 1)
        v += __shfl_xor(v, off, 64);
    return v;
}

__device__ __forceinline__ void wave_sum4(float& a, float& b, float& c, float& d) {
#pragma unroll
    for (int off = 32; off > 0; off >>= 1) {
        const float ax = __shfl_xor(a, off, 64);
        const float bx = __shfl_xor(b, off, 64);
        const float cx = __shfl_xor(c, off, 64);
        const float dx = __shfl_xor(d, off, 64);
        a += ax; b += bx; c += cx; d += dx;
    }
}

// Issue one row's 8 async DMA chunks (4 o + 4 t), 1 KB each.
__device__ __forceinline__ void issue_row(const float* __restrict__ outp,
                                          const float* __restrict__ tgtp,
                                          int row, int lane,
                                          float* lo, float* lt) {
    const float* orow = outp + (size_t)row * C_DIM;
    const float* trow = tgtp + (size_t)row * C_DIM;
#pragma unroll
    for (int it = 0; it < 4; ++it) {
        const int j  = lane + 64 * it;          // float4 index within row
        const int jj = (j < NV4) ? (j * 4) : 0; // clamp tail lanes in-bounds
        dma16(orow + jj, lo + it * CHUNK);
        dma16(trow + jj, lt + it * CHUNK);
    }
}

// One wave processes RPW consecutive rows through a private LDS double
// buffer fed by async global->LDS DMA. No __syncthreads in the loop.
__global__ __launch_bounds__(256) void mvce_rows(
    const float* __restrict__ outp, const float* __restrict__ tgtp,
    float* __restrict__ partial)
{
    // [wave][buf][o/t][ROWF] = 4*2*2*1024*4B = 64 KB
    __shared__ float lds[WPB][2][2][ROWF];

    const int lane = threadIdx.x & 63;
    const int wave = threadIdx.x >> 6;
    const int wgid = blockIdx.x * WPB + wave;
    const int row0 = wgid * RPW;

    // Prologue: prefetch row 0 into buffer 0.
    issue_row(outp, tgtp, row0, lane, lds[wave][0][0], lds[wave][0][1]);

    float wsum_lane = 0.0f;

#pragma unroll
    for (int r = 0; r < RPW; ++r) {
        const int buf = r & 1;
        // Prefetch next row into the other buffer before waiting.
        if (r + 1 < RPW)
            issue_row(outp, tgtp, row0 + r + 1, lane,
                      lds[wave][buf ^ 1][0], lds[wave][buf ^ 1][1]);

        // Wait for row r's 8 DMAs (allow the 8 newer ones to stay in flight).
        if (r + 1 < RPW) __builtin_amdgcn_s_waitcnt(0x0F78);  // vmcnt(8)
        else             __builtin_amdgcn_s_waitcnt(0x0F70);  // vmcnt(0)
        __builtin_amdgcn_sched_barrier(0);

        const float4* lo4 = reinterpret_cast<const float4*>(lds[wave][buf][0]);
        const float4* lt4 = reinterpret_cast<const float4*>(lds[wave][buf][1]);

        // Pass 1: negative-set stats + positive count (branchless).
        float S = 0.f, T = 0.f, A = 0.f, P = 0.f;
#pragma unroll
        for (int it = 0; it < 4; ++it) {
            float4 ov = lo4[lane + 64 * it];
            float4 tv = lt4[lane + 64 * it];
            if (it == 3 && lane >= 58) {   // tail: elements >= 1000
                ov = make_float4(PAD_O, PAD_O, PAD_O, PAD_O);
                tv = make_float4(0.f, 0.f, 0.f, 0.f);
            }
            const float oo[4] = {ov.x, ov.y, ov.z, ov.w};
            const float tt[4] = {tv.x, tv.y, tv.z, tv.w};
#pragma unroll
            for (int q = 0; q < 4; ++q) {
                const float e   = __expf(oo[q]);
                const bool  neg = (tt[q] <= 0.5f);
                const float tn  = neg ? tt[q] : 0.0f;
                S += neg ? e : 0.0f;
                T += tn;
                A  = fmaf(tn, oo[q], A);
                P += neg ? 0.0f : 1.0f;
            }
        }
        wave_sum4(S, T, A, P);   // Sneg, Tneg, Aneg, npos

        // Pass 2: positive-loss partial (re-read LDS, recompute exp).
        float L = 0.f;
#pragma unroll
        for (int it = 0; it < 4; ++it) {
            float4 ov = lo4[lane + 64 * it];
            float4 tv = lt4[lane + 64 * it];
            if (it == 3 && lane >= 58) {
                ov = make_float4(PAD_O, PAD_O, PAD_O, PAD_O);
                tv = make_float4(0.f, 0.f, 0.f, 0.f);
            }
            const float oo[4] = {ov.x, ov.y, ov.z, ov.w};
            const float tt[4] = {tv.x, tv.y, tv.z, tv.w};
#pragma unroll
            for (int q = 0; q < 4; ++q) {
                const float lse = __logf(S + __expf(oo[q]));
                const float b   = fmaf(tt[q], oo[q], A);
                const float c   = fmaf(T + tt[q], lse, -b);
                L += (tt[q] > 0.5f) ? c : 0.0f;
            }
        }

        if (P > 0.5f)       wsum_lane += L / P;
        else if (lane == 0) wsum_lane += fmaf(T, __logf(S), -A);  // rare fallback
    }

    const float wsum = wave_sum(wsum_lane);
    if (lane == 0) partial[wgid] = wsum;
}

__global__ __launch_bounds__(256) void mvce_reduce(
    const float* __restrict__ partial, int n4, float inv_b, float* __restrict__ out)
{
    const float4* p4 = reinterpret_cast<const float4*>(partial);
    float s = 0.f;
#pragma unroll 4
    for (int i = threadIdx.x; i < n4; i += 256) {
        const float4 v = p4[i];
        s += (v.x + v.y) + (v.z + v.w);
    }
    s = wave_sum(s);
    __shared__ float ls[4];
    const int lane = threadIdx.x & 63;
    const int wave = threadIdx.x >> 6;
    if (lane == 0) ls[wave] = s;
    __syncthreads();
    if (threadIdx.x == 0) out[0] = ((ls[0] + ls[1]) + (ls[2] + ls[3])) * inv_b;
}

extern "C" void kernel_launch(void* const* d_in, const int* in_sizes, int n_in,
                              void* d_out, int out_size, void* d_ws, size_t ws_size,
                              hipStream_t stream) {
    const float* outp = (const float*)d_in[0];
    const float* tgtp = (const float*)d_in[1];
    const int Bn = in_sizes[0] / C_DIM;              // 65536
    const int nblocks = Bn / (WPB * RPW);            // 2048 blocks
    const int nwaves  = nblocks * WPB;               // 8192 partials (32 KB ws)
    float* partial = (float*)d_ws;

    mvce_rows<<<nblocks, 256, 0, stream>>>(outp, tgtp, partial);
    mvce_reduce<<<1, 256, 0, stream>>>(partial, nwaves / 4, 1.0f / (float)Bn,
                                       (float*)d_out);
}